// Round 2
// baseline (169.298 us; speedup 1.0000x reference)
//
#include <hip/hip_runtime.h>
#include <hip/hip_bf16.h>

// RoI bilinear pooling.
// img : (1, H=200, W=200, C=256) fp32 NHWC -> channel vectors contiguous (1 KiB)
// rois: (1, N=2000, 4) fp32 (integer-valued x,y,w,h)
// out : (1, N, ps, ps, C) fp32
//
// One wave (64 lanes) per (roi, py) output row: the roi fetch + y-side math is
// done once per wave, then the px loop (unrolled x7 for ps==7) issues 4
// independent float4 loads per cell -> up to 28 loads in flight per wave.
// Output stores are non-temporal: the 100 MB output stream must not evict the
// 41 MB image from L3 (R0 post-mortem: FETCH_SIZE was 169 MB vs 41 MB ideal
// because write-allocate traffic thrashed Infinity Cache).

typedef float f32x4 __attribute__((ext_vector_type(4)));

__global__ __launch_bounds__(256) void RoIPool_53575422050620_kernel(
    const float* __restrict__ feat,   // H*W*C
    const float* __restrict__ rois,   // N*4
    const int*   __restrict__ psp,    // pool_size scalar
    float*       __restrict__ out,    // N*ps*ps*C
    int n_rows, int H, int W, int C)  // n_rows = N*ps
{
    const int ps  = psp[0];
    const int row = blockIdx.x * 4 + (threadIdx.x >> 6);   // (roi*ps + py)
    if (row >= n_rows) return;
    const int lane = threadIdx.x & 63;

    const int roi = row / ps;
    const int py  = row - roi * ps;

    const float4 r = reinterpret_cast<const float4*>(rois)[roi];
    const int x = (int)r.x;   // astype(int32) == trunc; values >= 0
    const int y = (int)r.y;
    const int w = (int)r.z;
    const int h = (int)r.w;

    // y-side math, identical fp32 expression to reference
    const float sy    = (float)h / (float)ps;
    const float sx    = (float)w / (float)ps;
    const float src_y = (float)py * sy;
    const int   y0    = (int)floorf(src_y);
    const float wy    = src_y - (float)y0;
    const float omwy  = 1.0f - wy;

    const int gy0 = min(max(y + min(max(y0,     0), h - 1), 0), H - 1);
    const int gy1 = min(max(y + min(max(y0 + 1, 0), h - 1), 0), H - 1);

    const int C4 = C >> 2;   // == 64: one float4 per lane covers the row
    const f32x4* __restrict__ f4 = reinterpret_cast<const f32x4*>(feat);
    f32x4* __restrict__ o4 = reinterpret_cast<f32x4*>(out);

    const size_t r0 = (size_t)(gy0 * W) * C4 + lane;
    const size_t r1 = (size_t)(gy1 * W) * C4 + lane;
    const size_t ob = (size_t)row * ps * C4 + lane;

    auto body = [&](int px) {
        const float src_x = (float)px * sx;
        const int   x0    = (int)floorf(src_x);
        const float wx    = src_x - (float)x0;
        const float omwx  = 1.0f - wx;

        const int gx0 = min(max(x + min(max(x0,     0), w - 1), 0), W - 1);
        const int gx1 = min(max(x + min(max(x0 + 1, 0), w - 1), 0), W - 1);

        const f32x4 v00 = f4[r0 + (size_t)gx0 * C4];
        const f32x4 v01 = f4[r0 + (size_t)gx1 * C4];
        const f32x4 v10 = f4[r1 + (size_t)gx0 * C4];
        const f32x4 v11 = f4[r1 + (size_t)gx1 * C4];

        // identical per-cell expression to the reference:
        // top = v00*(1-wx)+v01*wx ; bot = v10*(1-wx)+v11*wx ; out = top*(1-wy)+bot*wy
        const f32x4 top = v00 * omwx + v01 * wx;
        const f32x4 bot = v10 * omwx + v11 * wx;
        const f32x4 o   = top * omwy + bot * wy;

        __builtin_nontemporal_store(o, &o4[ob + (size_t)px * C4]);
    };

    if (ps == 7) {
#pragma unroll
        for (int px = 0; px < 7; ++px) body(px);
    } else {
        for (int px = 0; px < ps; ++px) body(px);
    }
}

extern "C" void kernel_launch(void* const* d_in, const int* in_sizes, int n_in,
                              void* d_out, int out_size, void* d_ws, size_t ws_size,
                              hipStream_t stream) {
    const float* img  = (const float*)d_in[0];
    const float* rois = (const float*)d_in[1];
    const int*   psp  = (const int*)d_in[2];
    float*       out  = (float*)d_out;

    const int H = 200, W = 200, C = 256;
    const int ps = 7;                            // fixed problem instance
    const int n_rows = out_size / (C * ps);      // N * ps = 14000
    const int blocks = (n_rows + 3) / 4;         // 4 waves (rows) per block

    RoIPool_53575422050620_kernel<<<blocks, 256, 0, stream>>>(
        img, rois, psp, out, n_rows, H, W, C);
}